// Round 1
// baseline (147.201 us; speedup 1.0000x reference)
//
#include <hip/hip_runtime.h>
#include <math.h>

#define G   50
#define T   24
#define B   128
#define NLP (B * T)
#define SZ  (B * G * T)   // 153600 elements per (B,G,T) output

typedef float v2f __attribute__((ext_vector_type(2)));

// d_out layout (floats, concatenated in return order):
//   [0,      SZ)        P_DA   (B,G,T)
//   [SZ,     2SZ)       R_up
//   [2SZ,    3SZ)       R_dn
//   [3SZ,    3SZ+B)     obj    (B,)
//   [3SZ+B,  4SZ+B)     Cost_DA

__device__ __forceinline__ v2f vmax0(v2f v) {
    v2f z = {0.f, 0.f};
    return __builtin_elementwise_max(v, z);
}

// DPP helper: row_ror rotate within 16-lane rows.
template <int CTRL>
__device__ __forceinline__ float dpp_mov(float x) {
    int r = __builtin_amdgcn_update_dpp(0, __float_as_int(x), CTRL, 0xf, 0xf, true);
    return __int_as_float(r);
}

// All-reduce 3 values within each 16-lane ROW — fused v_add_f32_dpp, 12
// instructions, chains interleaved so each register has >=2 intervening
// instructions between write and DPP read (2-wait-state hazard). s_nop 1
// guards against the compiler-emitted producer immediately preceding.
__device__ __forceinline__ void row_sum3(float& a, float& b, float& c) {
    asm("s_nop 1\n\t"
        "v_add_f32_dpp %0, %0, %0 row_ror:1 row_mask:0xf bank_mask:0xf\n\t"
        "v_add_f32_dpp %1, %1, %1 row_ror:1 row_mask:0xf bank_mask:0xf\n\t"
        "v_add_f32_dpp %2, %2, %2 row_ror:1 row_mask:0xf bank_mask:0xf\n\t"
        "v_add_f32_dpp %0, %0, %0 row_ror:2 row_mask:0xf bank_mask:0xf\n\t"
        "v_add_f32_dpp %1, %1, %1 row_ror:2 row_mask:0xf bank_mask:0xf\n\t"
        "v_add_f32_dpp %2, %2, %2 row_ror:2 row_mask:0xf bank_mask:0xf\n\t"
        "v_add_f32_dpp %0, %0, %0 row_ror:4 row_mask:0xf bank_mask:0xf\n\t"
        "v_add_f32_dpp %1, %1, %1 row_ror:4 row_mask:0xf bank_mask:0xf\n\t"
        "v_add_f32_dpp %2, %2, %2 row_ror:4 row_mask:0xf bank_mask:0xf\n\t"
        "v_add_f32_dpp %0, %0, %0 row_ror:8 row_mask:0xf bank_mask:0xf\n\t"
        "v_add_f32_dpp %1, %1, %1 row_ror:8 row_mask:0xf bank_mask:0xf\n\t"
        "v_add_f32_dpp %2, %2, %2 row_ror:8 row_mask:0xf bank_mask:0xf"
        : "+v"(a), "+v"(b), "+v"(c));
}

__device__ __forceinline__ float row_sum1(float a) {
    a += dpp_mov<0x121>(a);
    a += dpp_mov<0x122>(a);
    a += dpp_mov<0x124>(a);
    a += dpp_mov<0x128>(a);
    return a;
}

// 32-lane all-reduce (within each wave half): 16-lane DPP rows, then
// ds_swizzle xor-16 (BitMode 0x401F; lane permute within 32-lane groups,
// so it never crosses the LP boundary at lane 32).
__device__ __forceinline__ float half_sum1(float a) {
    a = row_sum1(a);
    float t;
    asm("ds_swizzle_b32 %0, %1 offset:0x401f\n\t"
        "s_waitcnt lgkmcnt(0)"
        : "=&v"(t) : "v"(a));
    return a + t;
}

// One wave per block; half h = lane>>5 (32 lanes) solves LP (2*blockIdx + h).
// Lane l (=lane&31) owns generators {l, l+32} in one v2f; slot .y valid iff
// l < 18 (50 gens total). Sentinel cost BIG clamps invalid slots to 0.
__global__ __launch_bounds__(64)
void pdhg_lp_kernel(const float* __restrict__ forecast,
                    const float* __restrict__ pmin,
                    const float* __restrict__ pmax,
                    const float* __restrict__ bcost,
                    const float* __restrict__ ccost,
                    const int*   __restrict__ n_iters_p,
                    float* __restrict__ out,
                    float* __restrict__ ws_partial,   // NLP floats (or null)
                    float tau)
{
    const int lane = threadIdx.x;         // 0..63
    const int l    = lane & 31;           // lane within half
    const int half = lane >> 5;           // LP slot within wave
    const int lp   = blockIdx.x * 2 + half;
    const int b    = lp / T;
    const int t    = lp - b * T;
    const int n_iters = n_iters_p[0];

    const int  g0 = l;                    // always < 50
    const int  g1 = l + 32;               // valid iff l < 18
    const bool v1 = (l < 18);

    v2f bj  = { bcost[g0], v1 ? bcost[g1] : 0.f };
    v2f cj  = { ccost[g0], v1 ? ccost[g1] : 0.f };
    v2f pmx = { pmax[g0],  v1 ? pmax[g1]  : 0.f };
    v2f pmn = { pmin[g0],  v1 ? pmin[g1]  : 0.f };
    const float f = forecast[lp];         // uniform within each half

    const float ts  = tau * tau;          // sigma == tau
    const float BIG = 1e30f;              // sentinel: clamps invalid slot to 0

    v2f tcP  = tau * bj;           if (!v1) tcP.y  = BIG;
    v2f tcRu = (tau * 0.05f) * bj; if (!v1) tcRu.y = BIG;
    v2f tcRd = (tau * 0.02f) * bj; if (!v1) tcRd.y = BIG;
    v2f tspmx = ts * pmx, tspmn = ts * pmn;
    const float tsf   = ts * f;
    const float tsreq = ts * 0.02f * f;   // REQ_UP_RATIO == REQ_DN_RATIO

    v2f P = {0,0}, Ru = {0,0}, Rd = {0,0};
    v2f z1 = {0,0}, z2 = {0,0}, z3 = {0,0}, z4 = {0,0};  // scaled duals tau*y
    float z0 = 0.f, zru = 0.f, zrd = 0.f;                // half-uniform

    for (int it = 0; it < n_iters; ++it) {
        // ---- x-update: x_new = max(x - (tau*c + tau*K^T y), 0) ----
        v2f z0v  = { z0,  z0  };
        v2f zruv = { zru, zru };
        v2f zrdv = { zrd, zrd };
        v2f gP  = (z1 - z2) + (z3 - z4) + z0v;
        v2f Pn  = vmax0(P  - tcP  - gP);
        v2f Run = vmax0(Ru - tcRu - z1 + zruv);
        v2f Rdn = vmax0(Rd - tcRd - z2 + zrdv);

        // overrelaxation: x_bar = 2*x_new - x_old
        v2f Pb  = 2.f * Pn  - P;
        v2f Rub = 2.f * Run - Ru;
        v2f Rdb = 2.f * Rdn - Rd;
        P = Pn; Ru = Run; Rd = Rdn;

        // ---- half-local sums over generators ----
        float sP  = Pb.x  + Pb.y;
        float sRu = Rub.x + Rub.y;
        float sRd = Rdb.x + Rdb.y;
        row_sum3(sP, sRu, sRd);            // 16-lane row sums (DPP)

        // issue cross-row xor-16 swizzles NOW; wait later so the
        // independent z1..z4 updates fill the LDS-pipe latency shadow
        float xP, xRu, xRd;
        asm("ds_swizzle_b32 %0, %3 offset:0x401f\n\t"
            "ds_swizzle_b32 %1, %4 offset:0x401f\n\t"
            "ds_swizzle_b32 %2, %5 offset:0x401f"
            : "=&v"(xP), "=&v"(xRu), "=&v"(xRd)
            : "v"(sP), "v"(sRu), "v"(sRd));

        // ---- z-update (sum-independent part): z += ts*(K x_bar - q) ----
        z1 = vmax0(z1 + ts * (Pb + Rub) - tspmx);        // P+Ru <= pmax
        z2 = vmax0(z2 + ts * (Rdb - Pb) + tspmn);        // -P+Rd <= -pmin
        z3 = vmax0(z3 + ts * Pb - tspmx);                // P <= pmax
        z4 = vmax0(z4 - ts * Pb + tspmn);                // -P <= -pmin

        asm("s_waitcnt lgkmcnt(0)" : "+v"(xP), "+v"(xRu), "+v"(xRd));
        sP += xP; sRu += xRu; sRd += xRd;

        z0  = z0 + ts * sP - tsf;                        // equality row
        zru = fmaxf(zru + tsreq - ts * sRu, 0.f);        // -sum Ru <= -req
        zrd = fmaxf(zrd + tsreq - ts * sRd, 0.f);        // -sum Rd <= -req
    }

    const v2f cost = bj * P + cj;
    {
        const int bgt = b * (G * T) + t;
        const int a0 = bgt + g0 * T;
        out[a0] = P.x;  out[SZ + a0] = Ru.x;  out[2*SZ + a0] = Rd.x;  out[3*SZ + B + a0] = cost.x;
        if (v1) {
            const int a1 = bgt + g1 * T;
            out[a1] = P.y;  out[SZ + a1] = Ru.y;  out[2*SZ + a1] = Rd.y;  out[3*SZ + B + a1] = cost.y;
        }
    }

    if (ws_partial) {
        // per-(b,t) objective partial: sum_g cost + 0.05*b*Ru + 0.02*b*Rd
        v2f lo = cost + (0.05f * bj) * Ru + (0.02f * bj) * Rd;
        float tot = half_sum1(lo.x + lo.y);
        if (l == 0) ws_partial[lp] = tot;
    }
}

// obj[b] = sum_t ws_partial[b*T + t]   (deterministic, tiny)
__global__ __launch_bounds__(64)
void obj_final_kernel(const float* __restrict__ ws_partial, float* __restrict__ out)
{
    const int b = blockIdx.x * 64 + threadIdx.x;
    if (b < B) {
        float s = 0.f;
        #pragma unroll
        for (int t = 0; t < T; ++t) s += ws_partial[b * T + t];
        out[3 * SZ + b] = s;
    }
}

// Fallback (ws too small): recompute obj from outputs, one block per b
__global__ __launch_bounds__(256)
void obj_kernel(const float* __restrict__ bcost, float* __restrict__ out)
{
    const int b = blockIdx.x;
    const float* Ru = out + SZ     + (size_t)b * (G * T);
    const float* Rd = out + 2 * SZ + (size_t)b * (G * T);
    const float* C  = out + 3 * SZ + B + (size_t)b * (G * T);

    float s = 0.f;
    for (int i = threadIdx.x; i < G * T; i += 256) {
        const int g = i / T;
        const float bg = bcost[g];
        s += C[i] + 0.05f * bg * Ru[i] + 0.02f * bg * Rd[i];
    }
    __shared__ float sm[16];
    s = row_sum1(s);                                 // 16-lane row sums
    if ((threadIdx.x & 15) == 0) sm[threadIdx.x >> 4] = s;
    __syncthreads();
    if (threadIdx.x == 0) {
        float tot = 0.f;
        #pragma unroll
        for (int i = 0; i < 16; ++i) tot += sm[i];
        out[3 * SZ + b] = tot;
    }
}

extern "C" void kernel_launch(void* const* d_in, const int* in_sizes, int n_in,
                              void* d_out, int out_size, void* d_ws, size_t ws_size,
                              hipStream_t stream) {
    const float* forecast = (const float*)d_in[0];
    const float* pmin_p   = (const float*)d_in[1];
    const float* pmax_p   = (const float*)d_in[2];
    const float* b_p      = (const float*)d_in[3];
    const float* c_p      = (const float*)d_in[4];
    const int*   niter_p  = (const int*)  d_in[5];
    float* out = (float*)d_out;

    // ||K||_2 analytic for this fixed 0/±1 structure (G=50):
    // K^T K = [[4I+J, I, -I],[I, I+J, 0],[-I, 0, I+J]]; largest eig on the
    // ones-subspace is (105+sqrt(17))/2  ->  L = sqrt((105+sqrt(17))/2)
    const double L = sqrt((105.0 + sqrt(17.0)) * 0.5);
    const float tau = (float)(0.9 / L);   // sigma == tau

    const bool use_ws = (ws_size >= (size_t)NLP * sizeof(float));
    float* wsp = use_ws ? (float*)d_ws : nullptr;

    // 32 lanes per LP, 2 LPs per wave -> 1536 waves (1.5/SIMD), vs 768 before
    pdhg_lp_kernel<<<NLP / 2, 64, 0, stream>>>(forecast, pmin_p, pmax_p,
                                               b_p, c_p, niter_p, out, wsp, tau);
    if (use_ws) {
        obj_final_kernel<<<(B + 63) / 64, 64, 0, stream>>>(wsp, out);
    } else {
        obj_kernel<<<B, 256, 0, stream>>>(b_p, out);
    }
}